// Round 1
// baseline (266.417 us; speedup 1.0000x reference)
//
#include <hip/hip_runtime.h>

#define N_NODES 100000
#define D 128
#define E_POS 262144
#define E_NEG 262144
#define E_TOT (E_POS + E_NEG)

// ---------------------------------------------------------------------------
// Phase 1: UV[n][j] for j<128 : sum_k x[n][k]*W1[k][j] + b1[j]         (U)
//          UV[n][128+j']      : sum_k x[n][k]*W1[128+k][j']            (V)
// Tile: 64 nodes x 64 cols per block, 256 threads, each thread 4x4 microtile.
// Grid: (ceil(N/64), 4)  -- blockIdx.y = column block (0,1 -> U; 2,3 -> V)
// ---------------------------------------------------------------------------
__global__ __launch_bounds__(256) void node_gemm(
    const float* __restrict__ x,    // [N, 128]
    const float* __restrict__ W1,   // [256, 128]
    const float* __restrict__ b1,   // [128]
    float* __restrict__ UV)         // [N, 256]
{
    __shared__ float xs[64][132];   // x tile, pad 4 floats (16B-aligned rows)
    __shared__ float wt[32][64];    // W chunk: 32 k-rows x 64 cols

    const int t  = threadIdx.x;
    const int tn = t >> 4;          // 0..15 node group
    const int tj = t & 15;          // 0..15 col group
    const int nb = blockIdx.x * 64;
    const int cb = blockIdx.y;               // 0..3
    const int rowoff = (cb >= 2) ? D : 0;    // W1 row offset (V half)
    const int coloff = (cb & 1) * 64;        // W1 col offset

    // Stage x tile [64][128] with float4 loads (2048 float4 / 256 thr = 8 each)
    for (int i = 0; i < 8; ++i) {
        int s  = t + i * 256;       // slot in [0,2048)
        int r  = s >> 5;            // row 0..63
        int c4 = s & 31;            // float4 col 0..31
        int n  = nb + r;
        float4 v = make_float4(0.f, 0.f, 0.f, 0.f);
        if (n < N_NODES) v = *(const float4*)(x + (size_t)n * D + c4 * 4);
        *(float4*)(&xs[r][c4 * 4]) = v;
    }

    float acc[4][4];
#pragma unroll
    for (int i = 0; i < 4; ++i)
#pragma unroll
        for (int q = 0; q < 4; ++q) acc[i][q] = 0.f;

    for (int k0 = 0; k0 < D; k0 += 32) {
        __syncthreads();   // first iter: covers x staging; later: wt reuse
        // Stage W chunk: rows k0..k0+31, cols coloff..coloff+63 (512 f4, 2/thr)
        for (int i = 0; i < 2; ++i) {
            int s  = t + i * 256;   // [0,512)
            int kk = s >> 4;        // 0..31
            int c4 = s & 15;        // 0..15
            float4 v = *(const float4*)(W1 + (size_t)(rowoff + k0 + kk) * D +
                                        coloff + c4 * 4);
            *(float4*)(&wt[kk][c4 * 4]) = v;
        }
        __syncthreads();

#pragma unroll
        for (int kk = 0; kk < 32; ++kk) {
            float4 w = *(const float4*)(&wt[kk][tj * 4]);
            int k = k0 + kk;
            float x0 = xs[tn * 4 + 0][k];
            float x1 = xs[tn * 4 + 1][k];
            float x2 = xs[tn * 4 + 2][k];
            float x3 = xs[tn * 4 + 3][k];
            acc[0][0] = fmaf(x0, w.x, acc[0][0]);
            acc[0][1] = fmaf(x0, w.y, acc[0][1]);
            acc[0][2] = fmaf(x0, w.z, acc[0][2]);
            acc[0][3] = fmaf(x0, w.w, acc[0][3]);
            acc[1][0] = fmaf(x1, w.x, acc[1][0]);
            acc[1][1] = fmaf(x1, w.y, acc[1][1]);
            acc[1][2] = fmaf(x1, w.z, acc[1][2]);
            acc[1][3] = fmaf(x1, w.w, acc[1][3]);
            acc[2][0] = fmaf(x2, w.x, acc[2][0]);
            acc[2][1] = fmaf(x2, w.y, acc[2][1]);
            acc[2][2] = fmaf(x2, w.z, acc[2][2]);
            acc[2][3] = fmaf(x2, w.w, acc[2][3]);
            acc[3][0] = fmaf(x3, w.x, acc[3][0]);
            acc[3][1] = fmaf(x3, w.y, acc[3][1]);
            acc[3][2] = fmaf(x3, w.z, acc[3][2]);
            acc[3][3] = fmaf(x3, w.w, acc[3][3]);
        }
    }

    // Epilogue: fold b1 into the U half (cb<2), store float4
    float4 badd = make_float4(0.f, 0.f, 0.f, 0.f);
    if (cb < 2) badd = *(const float4*)(b1 + coloff + tj * 4);
#pragma unroll
    for (int i = 0; i < 4; ++i) {
        int n = nb + tn * 4 + i;
        if (n >= N_NODES) continue;
        float4 v = make_float4(acc[i][0] + badd.x, acc[i][1] + badd.y,
                               acc[i][2] + badd.z, acc[i][3] + badd.w);
        *(float4*)(UV + (size_t)n * 256 + cb * 64 + tj * 4) = v;
    }
}

// ---------------------------------------------------------------------------
// Phase 2: per edge out[e] = relu(U[src]+V[tar]) . W2 + b2
// 2 edges per wave (32 lanes/edge, float4/lane). 256-thread blocks = 8 edges.
// ---------------------------------------------------------------------------
__global__ __launch_bounds__(256) void edge_score(
    const float* __restrict__ UV,
    const int* __restrict__ pos,    // [2, E_POS]
    const int* __restrict__ neg,    // [2, E_NEG]
    const float* __restrict__ W2,   // [128]
    const float* __restrict__ b2,   // [1]
    float* __restrict__ out)        // [E_TOT]
{
    const int t    = threadIdx.x;
    const int lane = t & 63;
    const int half = lane >> 5;     // 0/1: which edge in the wave
    const int l32  = lane & 31;
    const int wib  = t >> 6;        // wave in block 0..3
    const int e    = blockIdx.x * 8 + wib * 2 + half;   // E_TOT % 8 == 0

    int src, tar;
    if (e < E_POS) {
        src = pos[e];
        tar = pos[E_POS + e];
    } else {
        int e2 = e - E_POS;
        src = neg[e2];
        tar = neg[E_NEG + e2];
    }

    float4 u  = *(const float4*)(UV + (size_t)src * 256 + l32 * 4);
    float4 v  = *(const float4*)(UV + (size_t)tar * 256 + 128 + l32 * 4);
    float4 w2 = *(const float4*)(W2 + l32 * 4);

    float h0 = fmaxf(u.x + v.x, 0.f);
    float h1 = fmaxf(u.y + v.y, 0.f);
    float h2 = fmaxf(u.z + v.z, 0.f);
    float h3 = fmaxf(u.w + v.w, 0.f);
    float p = fmaf(h0, w2.x, fmaf(h1, w2.y, fmaf(h2, w2.z, h3 * w2.w)));

    // reduce within the 32-lane group (xor offsets < 32 stay in-group)
#pragma unroll
    for (int off = 16; off > 0; off >>= 1) p += __shfl_xor(p, off, 64);

    if (l32 == 0) out[e] = p + b2[0];
}

// ---------------------------------------------------------------------------
// Fallback (only if ws_size is too small): one wave per edge, direct compute.
// ---------------------------------------------------------------------------
__global__ __launch_bounds__(64) void edge_naive(
    const float* __restrict__ x,
    const int* __restrict__ pos, const int* __restrict__ neg,
    const float* __restrict__ W1, const float* __restrict__ b1,
    const float* __restrict__ W2, const float* __restrict__ b2,
    float* __restrict__ out)
{
    const int lane = threadIdx.x;
    for (int e = blockIdx.x; e < E_TOT; e += gridDim.x) {
        int src, tar;
        if (e < E_POS) { src = pos[e]; tar = pos[E_POS + e]; }
        else { int e2 = e - E_POS; src = neg[e2]; tar = neg[E_NEG + e2]; }
        const float* xsrc = x + (size_t)src * D;
        const float* xtar = x + (size_t)tar * D;
        int j = lane * 2;
        float h0 = b1[j], h1 = b1[j + 1];
        for (int k = 0; k < D; ++k) {
            float a = xsrc[k], b = xtar[k];
            h0 = fmaf(a, W1[(size_t)k * D + j],     h0);
            h0 = fmaf(b, W1[(size_t)(k + D) * D + j], h0);
            h1 = fmaf(a, W1[(size_t)k * D + j + 1],     h1);
            h1 = fmaf(b, W1[(size_t)(k + D) * D + j + 1], h1);
        }
        float p = fmaf(fmaxf(h0, 0.f), W2[j], fmaxf(h1, 0.f) * W2[j + 1]);
#pragma unroll
        for (int off = 32; off > 0; off >>= 1) p += __shfl_xor(p, off, 64);
        if (lane == 0) out[e] = p + b2[0];
    }
}

extern "C" void kernel_launch(void* const* d_in, const int* in_sizes, int n_in,
                              void* d_out, int out_size, void* d_ws, size_t ws_size,
                              hipStream_t stream) {
    const float* x   = (const float*)d_in[0];
    const int*   pos = (const int*)d_in[1];
    const int*   neg = (const int*)d_in[2];
    const float* W1  = (const float*)d_in[3];
    const float* b1  = (const float*)d_in[4];
    const float* W2  = (const float*)d_in[5];
    const float* b2  = (const float*)d_in[6];
    float* out = (float*)d_out;

    const size_t need = (size_t)N_NODES * 256 * sizeof(float);
    if (ws_size >= need) {
        float* UV = (float*)d_ws;
        dim3 g1((N_NODES + 63) / 64, 4);
        node_gemm<<<g1, 256, 0, stream>>>(x, W1, b1, UV);
        edge_score<<<E_TOT / 8, 256, 0, stream>>>(UV, pos, neg, W2, b2, out);
    } else {
        edge_naive<<<8192, 64, 0, stream>>>(x, pos, neg, W1, b1, W2, b2, out);
    }
}

// Round 2
// 170.456 us; speedup vs baseline: 1.5630x; 1.5630x over previous
//
#include <hip/hip_runtime.h>

#define N_NODES 100000
#define D 128
#define E_POS 262144
#define E_NEG 262144
#define E_TOT (E_POS + E_NEG)

typedef __attribute__((ext_vector_type(8))) short short8;  // 8 bf16 (4 VGPRs)
typedef __attribute__((ext_vector_type(4))) float f4;      // MFMA C/D frag

__device__ __forceinline__ unsigned f2bf_u(float f) {
    // round-to-nearest-even fp32 -> bf16 (inputs are finite; no NaN path)
    unsigned u = __float_as_uint(f);
    return (u + 0x7fffu + ((u >> 16) & 1u)) >> 16;
}

// ---------------------------------------------------------------------------
// Phase 1 (bf16 MFMA): UVb[n][j] (bf16) =
//   j<128 : sum_k x[n][k]*W1[k][j] + b1[j]      (U)
//   j>=128: sum_k x[n][k]*W1[128+k][j-128]      (V)
// Block: 256 thr = 4 waves; 64 rows x 256 cols per block; each wave 64x64.
// A/B frags loaded straight from global (W1 is L1/L2-resident; x streamed)
// and converted to bf16 in-register. Epilogue transposes through LDS so the
// global store is row-major dwordx4.
// MFMA layouts (measured, m89/m91): A[m=lane&15][k=(lane>>4)*8+j],
// B[k=(lane>>4)*8+j][n=lane&15], C: col=lane&15, row=(lane>>4)*4+reg.
// ---------------------------------------------------------------------------
__global__ __launch_bounds__(256) void node_gemm_mfma(
    const float* __restrict__ x,            // [N, 128]
    const float* __restrict__ W1,           // [256, 128]
    const float* __restrict__ b1,           // [128]
    unsigned short* __restrict__ UVb)       // [N, 256] bf16
{
    __shared__ unsigned short Ls[64][264];  // 64 rows x 256 cols, +8 pad

    const int t    = threadIdx.x;
    const int w    = t >> 6;                // wave 0..3 -> col slice w*64
    const int lane = t & 63;
    const int m16  = lane & 15;
    const int q    = lane >> 4;             // quad 0..3
    const int nb   = blockIdx.x * 64;
    const int rowoff = (w < 2) ? 0 : D;     // W1 row offset (V half)
    const int cbase  = (w & 1) * 64;        // W1 col base for this wave

    f4 acc[4][4];
#pragma unroll
    for (int i = 0; i < 4; ++i)
#pragma unroll
        for (int j = 0; j < 4; ++j) acc[i][j] = (f4){0.f, 0.f, 0.f, 0.f};

    int rows[4];
#pragma unroll
    for (int rt = 0; rt < 4; ++rt) {
        int r = nb + rt * 16 + m16;
        rows[rt] = (r < N_NODES) ? r : (N_NODES - 1);  // clamp; store guarded
    }

#pragma unroll
    for (int ks = 0; ks < 4; ++ks) {
        const int k0 = ks * 32 + q * 8;     // this lane's 8 consecutive k
        short8 af[4], bfr[4];
#pragma unroll
        for (int rt = 0; rt < 4; ++rt) {
            const float* px = x + (size_t)rows[rt] * D + k0;
            const float4 a0 = *(const float4*)px;
            const float4 a1 = *(const float4*)(px + 4);
            short8 s;
            s[0] = (short)f2bf_u(a0.x); s[1] = (short)f2bf_u(a0.y);
            s[2] = (short)f2bf_u(a0.z); s[3] = (short)f2bf_u(a0.w);
            s[4] = (short)f2bf_u(a1.x); s[5] = (short)f2bf_u(a1.y);
            s[6] = (short)f2bf_u(a1.z); s[7] = (short)f2bf_u(a1.w);
            af[rt] = s;
        }
#pragma unroll
        for (int ct = 0; ct < 4; ++ct) {
            const int c = cbase + ct * 16 + m16;
            const float* pw = W1 + (size_t)(rowoff + k0) * D + c;
            short8 s;
#pragma unroll
            for (int j = 0; j < 8; ++j)
                s[j] = (short)f2bf_u(pw[(size_t)j * D]);
            bfr[ct] = s;
        }
#pragma unroll
        for (int rt = 0; rt < 4; ++rt)
#pragma unroll
            for (int ct = 0; ct < 4; ++ct)
                acc[rt][ct] = __builtin_amdgcn_mfma_f32_16x16x32_bf16(
                    af[rt], bfr[ct], acc[rt][ct], 0, 0, 0);
    }

    // b1 folds into the U half only (cols < 128 -> waves 0,1)
    float badd[4];
#pragma unroll
    for (int ct = 0; ct < 4; ++ct) {
        const int cg = w * 64 + ct * 16 + m16;
        badd[ct] = (w < 2) ? b1[cg] : 0.f;
    }

    // scatter C-frags (bf16) into LDS row-major
#pragma unroll
    for (int rt = 0; rt < 4; ++rt)
#pragma unroll
        for (int ct = 0; ct < 4; ++ct) {
            const int colg = w * 64 + ct * 16 + m16;
#pragma unroll
            for (int r = 0; r < 4; ++r) {
                const int row = rt * 16 + q * 4 + r;
                Ls[row][colg] =
                    (unsigned short)f2bf_u(acc[rt][ct][r] + badd[ct]);
            }
        }
    __syncthreads();

    // coalesced bf16 store: thread t -> row t>>2, 64-col chunk (t&3)
    const int r  = t >> 2;
    const int c0 = (t & 3) * 64;
    const int grow = nb + r;
    if (grow < N_NODES) {
        const uint4* s = (const uint4*)&Ls[r][c0];
        uint4* d = (uint4*)(UVb + (size_t)grow * 256 + c0);
#pragma unroll
        for (int i = 0; i < 8; ++i) d[i] = s[i];
    }
}

// ---------------------------------------------------------------------------
// Phase 2: out[e] = relu(U[src]+V[tar]) . W2 + b2, UV in bf16.
// 16 lanes per edge, 16 B (8 bf16) per lane; 4 edges/wave, 16 edges/block.
// ---------------------------------------------------------------------------
__global__ __launch_bounds__(256) void edge_score_bf(
    const unsigned short* __restrict__ UVb,
    const int* __restrict__ pos,            // [2, E_POS]
    const int* __restrict__ neg,            // [2, E_NEG]
    const float* __restrict__ W2,           // [128]
    const float* __restrict__ b2,           // [1]
    float* __restrict__ out)                // [E_TOT]
{
    const int t    = threadIdx.x;
    const int lane = t & 63;
    const int l16  = lane & 15;
    const int sub  = lane >> 4;             // edge within wave
    const int w    = t >> 6;
    const int e    = blockIdx.x * 16 + w * 4 + sub;  // E_POS%16==0: uniform

    int src, tar;
    if (e < E_POS) {
        src = pos[e];
        tar = pos[E_POS + e];
    } else {
        const int e2 = e - E_POS;
        src = neg[e2];
        tar = neg[E_NEG + e2];
    }

    const uint4 uu = *(const uint4*)(UVb + (size_t)src * 256 + l16 * 8);
    const uint4 vv = *(const uint4*)(UVb + (size_t)tar * 256 + 128 + l16 * 8);
    const float4 wa = *(const float4*)(W2 + l16 * 8);
    const float4 wb = *(const float4*)(W2 + l16 * 8 + 4);

    float p = 0.f;
#define BF_LO(uv) __uint_as_float((uv) << 16)
#define BF_HI(uv) __uint_as_float((uv) & 0xffff0000u)
    p = fmaf(fmaxf(BF_LO(uu.x) + BF_LO(vv.x), 0.f), wa.x, p);
    p = fmaf(fmaxf(BF_HI(uu.x) + BF_HI(vv.x), 0.f), wa.y, p);
    p = fmaf(fmaxf(BF_LO(uu.y) + BF_LO(vv.y), 0.f), wa.z, p);
    p = fmaf(fmaxf(BF_HI(uu.y) + BF_HI(vv.y), 0.f), wa.w, p);
    p = fmaf(fmaxf(BF_LO(uu.z) + BF_LO(vv.z), 0.f), wb.x, p);
    p = fmaf(fmaxf(BF_HI(uu.z) + BF_HI(vv.z), 0.f), wb.y, p);
    p = fmaf(fmaxf(BF_LO(uu.w) + BF_LO(vv.w), 0.f), wb.z, p);
    p = fmaf(fmaxf(BF_HI(uu.w) + BF_HI(vv.w), 0.f), wb.w, p);
#undef BF_LO
#undef BF_HI

#pragma unroll
    for (int off = 8; off; off >>= 1) p += __shfl_xor(p, off, 64);

    if (l16 == 0) out[e] = p + b2[0];
}

// ---------------------------------------------------------------------------
// Fallback (ws too small): one wave per edge, direct fp32 compute.
// ---------------------------------------------------------------------------
__global__ __launch_bounds__(64) void edge_naive(
    const float* __restrict__ x,
    const int* __restrict__ pos, const int* __restrict__ neg,
    const float* __restrict__ W1, const float* __restrict__ b1,
    const float* __restrict__ W2, const float* __restrict__ b2,
    float* __restrict__ out)
{
    const int lane = threadIdx.x;
    for (int e = blockIdx.x; e < E_TOT; e += gridDim.x) {
        int src, tar;
        if (e < E_POS) { src = pos[e]; tar = pos[E_POS + e]; }
        else { int e2 = e - E_POS; src = neg[e2]; tar = neg[E_NEG + e2]; }
        const float* xsrc = x + (size_t)src * D;
        const float* xtar = x + (size_t)tar * D;
        int j = lane * 2;
        float h0 = b1[j], h1 = b1[j + 1];
        for (int k = 0; k < D; ++k) {
            float a = xsrc[k], b = xtar[k];
            h0 = fmaf(a, W1[(size_t)k * D + j],       h0);
            h0 = fmaf(b, W1[(size_t)(k + D) * D + j], h0);
            h1 = fmaf(a, W1[(size_t)k * D + j + 1],       h1);
            h1 = fmaf(b, W1[(size_t)(k + D) * D + j + 1], h1);
        }
        float p = fmaf(fmaxf(h0, 0.f), W2[j], fmaxf(h1, 0.f) * W2[j + 1]);
#pragma unroll
        for (int off = 32; off > 0; off >>= 1) p += __shfl_xor(p, off, 64);
        if (lane == 0) out[e] = p + b2[0];
    }
}

extern "C" void kernel_launch(void* const* d_in, const int* in_sizes, int n_in,
                              void* d_out, int out_size, void* d_ws, size_t ws_size,
                              hipStream_t stream) {
    const float* x   = (const float*)d_in[0];
    const int*   pos = (const int*)d_in[1];
    const int*   neg = (const int*)d_in[2];
    const float* W1  = (const float*)d_in[3];
    const float* b1  = (const float*)d_in[4];
    const float* W2  = (const float*)d_in[5];
    const float* b2  = (const float*)d_in[6];
    float* out = (float*)d_out;

    const size_t need = (size_t)N_NODES * 256 * sizeof(unsigned short);
    if (ws_size >= need) {
        unsigned short* UVb = (unsigned short*)d_ws;
        node_gemm_mfma<<<(N_NODES + 63) / 64, 256, 0, stream>>>(x, W1, b1, UVb);
        edge_score_bf<<<E_TOT / 16, 256, 0, stream>>>(UVb, pos, neg, W2, b2, out);
    } else {
        edge_naive<<<8192, 64, 0, stream>>>(x, pos, neg, W1, b1, W2, b2, out);
    }
}